// Round 3
// baseline (95.719 us; speedup 1.0000x reference)
//
#include <hip/hip_runtime.h>
#include <cstdint>

#define CIN 96
#define DIN 96
#define DTR 8
#define DST 16
#define HH 128
#define WW 128
#define HW (HH*WW)
#define NPIX (2*HW)   // B=2
#define DIAG (WW+1)   // diagonal step back = 129
#define PPB 8         // pixels per scan block

__device__ __forceinline__ float softplus_f(float t) {
    return (t > 20.0f) ? t : __logf(1.0f + __expf(t));
}

// ---------------- Stage 1: dBC matvec (40 outputs) + x transpose ----------------
// 512 blocks x 512 threads; block = 64 pixels; wave g computes outputs [5g,5g+5)
// for all 64 pixels (lane = pixel) and writes the x-transpose slice ch in [12g,12g+12).
__global__ __launch_bounds__(512) void ssm2d_dbc(
    const float* __restrict__ x,
    const float* __restrict__ W1, const float* __restrict__ b1,
    float* __restrict__ dbc, float* __restrict__ xws)
{
    const int lane = threadIdx.x & 63;
    const int g = __builtin_amdgcn_readfirstlane(threadIdx.x >> 6); // 0..7 uniform
    const int og = g * 5;
    const int p0 = blockIdx.x * 64;
    const int p = p0 + lane;
    const int bb = p0 >> 14;                 // batch (blocks never straddle)
    const int q = p & (HW - 1);
    const float* xb = x + (size_t)bb * CIN * HW + q;

    float a0 = b1[og + 0], a1 = b1[og + 1], a2 = b1[og + 2], a3 = b1[og + 3], a4 = b1[og + 4];
    const int chlo = g * 12;

    float buf0 = 0.f, buf1 = 0.f, buf2 = 0.f, buf3 = 0.f;
    #pragma unroll
    for (int ch = 0; ch < CIN; ++ch) {
        float xv = xb[(size_t)ch * HW];
        a0 = fmaf(xv, W1[(og + 0) * CIN + ch], a0);
        a1 = fmaf(xv, W1[(og + 1) * CIN + ch], a1);
        a2 = fmaf(xv, W1[(og + 2) * CIN + ch], a2);
        a3 = fmaf(xv, W1[(og + 3) * CIN + ch], a3);
        a4 = fmaf(xv, W1[(og + 4) * CIN + ch], a4);
        if (ch - chlo >= 0 && ch - chlo < 12) {      // wave-uniform branch
            switch (ch & 3) {
                case 0: buf0 = xv; break;
                case 1: buf1 = xv; break;
                case 2: buf2 = xv; break;
                default:
                    buf3 = xv;
                    *reinterpret_cast<float4*>(xws + (size_t)p * DIN + (ch & ~3)) =
                        make_float4(buf0, buf1, buf2, buf3);
            }
        }
    }

    float* dr = dbc + (size_t)p * 40 + og;
    dr[0] = a0; dr[1] = a1; dr[2] = a2; dr[3] = a3; dr[4] = a4;
}

// ---------------- Stage 2: short chains (L <= 16), LDS-shared, 8 px / 768-thread block ----------------
__global__ __launch_bounds__(768) void ssm2d_scan(
    const float* __restrict__ dbc, const float* __restrict__ xws,
    const float* __restrict__ dtw, const float* __restrict__ dtb,
    const float* __restrict__ alog, const float* __restrict__ Dv,
    float* __restrict__ out)
{
    __shared__ float sRow[PPB][40];      // k(8) | B(16) | C(16) per pixel
    __shared__ float sBC[PPB];           // dot(B, C) per pixel
    __shared__ float sdtwT[DTR][DIN];    // dt_w transposed
    __shared__ float sdtb[DIN];
    __shared__ float sDv[DIN];
    __shared__ float sAnT[DST][DIN];     // -exp(A_log) transposed [n][d]

    const int t = threadIdx.x;
    const int p0 = blockIdx.x * PPB;

    if (t < PPB * 40) sRow[t / 40][t % 40] = dbc[(size_t)p0 * 40 + t];
    sdtwT[t & 7][t >> 3] = dtw[t];                       // t in [0,768): d=t>>3, k=t&7
    if (t < DIN) { sdtb[t] = dtb[t]; sDv[t] = Dv[t]; }
    {
        int e0 = t, e1 = t + 768;                        // alog idx = d*16+n
        sAnT[e0 & 15][e0 >> 4] = -__expf(alog[e0]);
        sAnT[e1 & 15][e1 >> 4] = -__expf(alog[e1]);
    }
    __syncthreads();
    if (t < PPB) {
        float s = 0.f;
        #pragma unroll
        for (int n = 0; n < DST; ++n) s += sRow[t][8 + n] * sRow[t][24 + n];
        sBC[t] = s;
    }
    __syncthreads();

    const int lp = t / DIN;
    const int d = t - lp * DIN;
    const int p = p0 + lp;
    const int q = p & (HW - 1);
    const int r = q >> 7;
    const int c = q & (WW - 1);
    int m = __builtin_ctz(r + 1);
    int mc = __builtin_ctz(c + 1);
    if (mc < m) m = mc;
    if (m >= 5) return;                  // long chains handled by stage 3

    float wk[8];
    #pragma unroll
    for (int k = 0; k < 8; ++k) wk[k] = sdtwT[k][d];
    float tbv = sdtb[d];

    float tt = tbv;
    #pragma unroll
    for (int k = 0; k < 8; ++k) tt = fmaf(sRow[lp][k], wk[k], tt);
    float delta0 = softplus_f(tt);
    float x0 = xws[(size_t)p0 * DIN + t];
    float y = x0 * fmaf(delta0, sBC[lp], sDv[d]);

    if (m >= 1) {
        int L = 1 << m;
        float An[16], acc[16];
        #pragma unroll
        for (int n = 0; n < 16; ++n) { An[n] = sAnT[n][d]; acc[n] = 0.f; }
        float S = delta0;
        int pj = p;
        for (int j = 1; j < L; ++j) {
            pj -= DIAG;
            const float* rj = dbc + (size_t)pj * 40;
            float4 j0 = *reinterpret_cast<const float4*>(rj);
            float4 j1 = *reinterpret_cast<const float4*>(rj + 4);
            float t2 = tbv;
            t2 = fmaf(j0.x, wk[0], t2); t2 = fmaf(j0.y, wk[1], t2);
            t2 = fmaf(j0.z, wk[2], t2); t2 = fmaf(j0.w, wk[3], t2);
            t2 = fmaf(j1.x, wk[4], t2); t2 = fmaf(j1.y, wk[5], t2);
            t2 = fmaf(j1.z, wk[6], t2); t2 = fmaf(j1.w, wk[7], t2);
            float dj = softplus_f(t2);
            float xj = xws[(size_t)pj * DIN + d];
            float cj = dj * xj;
            float4 B0 = *reinterpret_cast<const float4*>(rj + 8);
            float4 B1 = *reinterpret_cast<const float4*>(rj + 12);
            float4 B2 = *reinterpret_cast<const float4*>(rj + 16);
            float4 B3 = *reinterpret_cast<const float4*>(rj + 20);
            float Bv[16] = {B0.x,B0.y,B0.z,B0.w, B1.x,B1.y,B1.z,B1.w,
                            B2.x,B2.y,B2.z,B2.w, B3.x,B3.y,B3.z,B3.w};
            #pragma unroll
            for (int n = 0; n < 16; ++n)
                acc[n] = fmaf(__expf(An[n] * S) * Bv[n], cj, acc[n]);
            S += dj;
        }
        float ys = 0.f;
        #pragma unroll
        for (int n = 0; n < 16; ++n) ys = fmaf(acc[n], sRow[lp][24 + n], ys);
        y += ys;
    }
    out[(size_t)p0 * DIN + t] = y;
}

// ---------------- Stage 3: long chains (L >= 32), one wave per (pixel, d) ----------------
__global__ __launch_bounds__(256) void ssm2d_scan_long(
    const float* __restrict__ dbc, const float* __restrict__ xws,
    const float* __restrict__ dtw, const float* __restrict__ dtb,
    const float* __restrict__ alog, const float* __restrict__ Dv,
    float* __restrict__ out)
{
    int wave = blockIdx.x * 4 + (threadIdx.x >> 6);   // 0..3071
    int lane = threadIdx.x & 63;
    int pix = wave / DIN;            // 0..31
    int d = wave - pix * DIN;
    int batch = pix >> 4;
    int sel = pix & 15;
    int r = ((sel >> 2) + 1) * 32 - 1;   // 31,63,95,127
    int c = ((sel & 3) + 1) * 32 - 1;
    int p = batch * HW + r * WW + c;
    int m = __builtin_ctz(r + 1);
    int mc = __builtin_ctz(c + 1);
    if (mc < m) m = mc;
    int L = 1 << m;                       // 32, 64, or 128

    float4 w0 = *reinterpret_cast<const float4*>(dtw + d * DTR);
    float4 w1 = *reinterpret_cast<const float4*>(dtw + d * DTR + 4);
    float tb = dtb[d];
    float An[16];
    #pragma unroll
    for (int n = 0; n < 16; ++n) An[n] = -__expf(alog[d * DST + n]);

    float acc[16];
    #pragma unroll
    for (int n = 0; n < 16; ++n) acc[n] = 0.0f;
    float Scarry = 0.0f;
    float x0 = 0.0f;

    for (int jb = 0; jb < L; jb += 64) {
        int j = jb + lane;
        bool act = (j < L);
        int jc = act ? j : 0;
        int pj = p - DIAG * jc;
        const float* rj = dbc + (size_t)pj * 40;
        float4 j0 = *reinterpret_cast<const float4*>(rj);
        float4 j1 = *reinterpret_cast<const float4*>(rj + 4);
        float tt = tb;
        tt = fmaf(j0.x, w0.x, tt); tt = fmaf(j0.y, w0.y, tt);
        tt = fmaf(j0.z, w0.z, tt); tt = fmaf(j0.w, w0.w, tt);
        tt = fmaf(j1.x, w1.x, tt); tt = fmaf(j1.y, w1.y, tt);
        tt = fmaf(j1.z, w1.z, tt); tt = fmaf(j1.w, w1.w, tt);
        float dj = softplus_f(tt);
        float xj = xws[(size_t)pj * DIN + d];
        if (!act) { dj = 0.0f; xj = 0.0f; }
        float cj = dj * xj;
        if (jb == 0) x0 = __shfl(xj, 0);

        // inclusive prefix-sum of dj over the wave
        float incl = dj;
        #pragma unroll
        for (int off = 1; off < 64; off <<= 1) {
            float v = __shfl_up(incl, off);
            if (lane >= off) incl += v;
        }
        float S = Scarry + incl - dj;     // exclusive prefix + carry

        float4 B0 = *reinterpret_cast<const float4*>(rj + 8);
        float4 B1 = *reinterpret_cast<const float4*>(rj + 12);
        float4 B2 = *reinterpret_cast<const float4*>(rj + 16);
        float4 B3 = *reinterpret_cast<const float4*>(rj + 20);
        float Bv[16] = {B0.x,B0.y,B0.z,B0.w, B1.x,B1.y,B1.z,B1.w,
                        B2.x,B2.y,B2.z,B2.w, B3.x,B3.y,B3.z,B3.w};
        #pragma unroll
        for (int n = 0; n < 16; ++n)
            acc[n] = fmaf(__expf(An[n] * S) * Bv[n], cj, acc[n]);

        Scarry += __shfl(incl, 63);
    }

    // butterfly reduce the 16 accumulators across the wave
    #pragma unroll
    for (int off = 32; off >= 1; off >>= 1) {
        #pragma unroll
        for (int n = 0; n < 16; ++n) acc[n] += __shfl_xor(acc[n], off);
    }

    if (lane == 0) {
        const float* rowd = dbc + (size_t)p * 40;
        float4 C0 = *reinterpret_cast<const float4*>(rowd + 24);
        float4 C1 = *reinterpret_cast<const float4*>(rowd + 28);
        float4 C2 = *reinterpret_cast<const float4*>(rowd + 32);
        float4 C3 = *reinterpret_cast<const float4*>(rowd + 36);
        float y = 0.0f;
        y = fmaf(acc[0],C0.x,y); y = fmaf(acc[1],C0.y,y); y = fmaf(acc[2],C0.z,y); y = fmaf(acc[3],C0.w,y);
        y = fmaf(acc[4],C1.x,y); y = fmaf(acc[5],C1.y,y); y = fmaf(acc[6],C1.z,y); y = fmaf(acc[7],C1.w,y);
        y = fmaf(acc[8],C2.x,y); y = fmaf(acc[9],C2.y,y); y = fmaf(acc[10],C2.z,y); y = fmaf(acc[11],C2.w,y);
        y = fmaf(acc[12],C3.x,y); y = fmaf(acc[13],C3.y,y); y = fmaf(acc[14],C3.z,y); y = fmaf(acc[15],C3.w,y);
        y = fmaf(Dv[d], x0, y);
        out[(size_t)p * DIN + d] = y;
    }
}

extern "C" void kernel_launch(void* const* d_in, const int* in_sizes, int n_in,
                              void* d_out, int out_size, void* d_ws, size_t ws_size,
                              hipStream_t stream) {
    const float* x    = (const float*)d_in[0];
    const float* W1   = (const float*)d_in[1];
    const float* b1   = (const float*)d_in[2];
    const float* dtw  = (const float*)d_in[3];
    const float* dtb  = (const float*)d_in[4];
    const float* alog = (const float*)d_in[5];
    const float* Dv   = (const float*)d_in[6];
    float* out = (float*)d_out;

    char* ws = (char*)d_ws;
    float* dbc = (float*)(ws);                 // NPIX*40 f32 = 5,242,880 B
    float* xws = (float*)(ws + 5242880);       // NPIX*96 f32 = 12,582,912 B

    hipLaunchKernelGGL(ssm2d_dbc, dim3(NPIX / 64), dim3(512), 0, stream,
                       x, W1, b1, dbc, xws);
    hipLaunchKernelGGL(ssm2d_scan_long, dim3(768), dim3(256), 0, stream,
                       dbc, xws, dtw, dtb, alog, Dv, out);
    hipLaunchKernelGGL(ssm2d_scan, dim3((NPIX * DIN) / (PPB * DIN)), dim3(PPB * DIN), 0, stream,
                       dbc, xws, dtw, dtb, alog, Dv, out);
}

// Round 4
// 61.692 us; speedup vs baseline: 1.5516x; 1.5516x over previous
//
#include <hip/hip_runtime.h>
#include <cstdint>

#define CIN 96
#define DIN 96
#define DTR 8
#define DST 16
#define HH 128
#define WW 128
#define HW (HH*WW)
#define NPIX (2*HW)   // B=2
#define DIAG (WW+1)   // diagonal step back = 129
#define SHORT_BLOCKS 8192   // NPIX/4
#define LONG_BLOCKS 512     // 32 px * 96 d = 3072 waves / 6 waves-per-block

__device__ __forceinline__ float softplus_f(float t) {
    return (t > 20.0f) ? t : __logf(1.0f + __expf(t));
}

// ---------------- Stage 1: dBC matvec + transposes + tables ----------------
// 512 blocks x 256 threads; block = 64 pixels. Wave w computes outputs [10w,10w+10).
__global__ __launch_bounds__(256) void ssm2d_dbc(
    const float* __restrict__ x,
    const float* __restrict__ W1, const float* __restrict__ b1,
    const float* __restrict__ dtw, const float* __restrict__ alog,
    float* __restrict__ dbc, float* __restrict__ xws, float* __restrict__ bcws,
    float* __restrict__ dtwT, float* __restrict__ Aws)
{
    __shared__ float sX[CIN][65];     // padded: conflict-free both axes
    __shared__ float sOut[64][41];    // 40 outputs per pixel, padded

    const int t = threadIdx.x;
    const int p0 = blockIdx.x * 64;
    const int bb = p0 >> 14;
    const int q0 = p0 & (HW - 1);
    const float* xb = x + (size_t)bb * CIN * HW + q0;

    // load x tile (96 ch x 64 px) as float4
    #pragma unroll
    for (int it = 0; it < 6; ++it) {
        int i = it * 256 + t;               // < 1536
        int ch = i >> 4;
        int p4 = (i & 15) << 2;
        float4 v = *reinterpret_cast<const float4*>(xb + (size_t)ch * HW + p4);
        sX[ch][p4 + 0] = v.x; sX[ch][p4 + 1] = v.y;
        sX[ch][p4 + 2] = v.z; sX[ch][p4 + 3] = v.w;
    }
    if (blockIdx.x == 0) {   // one-time transposed tables
        for (int i = t; i < DIN * DST; i += 256) {
            int d = i >> 4, n = i & 15;
            Aws[n * DIN + d] = -__expf(alog[i]);
        }
        for (int i = t; i < DIN * DTR; i += 256) {
            int d = i >> 3, k = i & 7;
            dtwT[k * DIN + d] = dtw[i];
        }
    }
    __syncthreads();

    const int lane = t & 63;
    const int w = __builtin_amdgcn_readfirstlane(t >> 6);   // 0..3
    const int og = w * 10;

    float acc[10];
    #pragma unroll
    for (int o = 0; o < 10; ++o) acc[o] = b1[og + o];
    #pragma unroll 8
    for (int ch = 0; ch < CIN; ++ch) {
        float xv = sX[ch][lane];
        #pragma unroll
        for (int o = 0; o < 10; ++o)
            acc[o] = fmaf(xv, W1[(og + o) * CIN + ch], acc[o]);
    }
    #pragma unroll
    for (int o = 0; o < 10; ++o) sOut[lane][og + o] = acc[o];
    __syncthreads();

    // per-pixel dot(B, C)
    if (t < 64) {
        float s = 0.f;
        #pragma unroll
        for (int n = 0; n < DST; ++n) s += sOut[t][8 + n] * sOut[t][24 + n];
        bcws[p0 + t] = s;
    }
    // dbc writeout (64 px x 40), coalesced float4
    for (int i = t; i < 640; i += 256) {
        int px = i / 10;
        int o4 = (i - px * 10) << 2;
        float4 v = make_float4(sOut[px][o4], sOut[px][o4 + 1],
                               sOut[px][o4 + 2], sOut[px][o4 + 3]);
        *reinterpret_cast<float4*>(dbc + (size_t)(p0 + px) * 40 + o4) = v;
    }
    // xws writeout (pixel-major transpose of x), coalesced float4
    #pragma unroll
    for (int it = 0; it < 6; ++it) {
        int i = it * 256 + t;               // < 1536
        int px = i / 24;
        int c4 = (i - px * 24) << 2;
        float4 v = make_float4(sX[c4][px], sX[c4 + 1][px],
                               sX[c4 + 2][px], sX[c4 + 3][px]);
        *reinterpret_cast<float4*>(xws + (size_t)(p0 + px) * DIN + c4) = v;
    }
}

// ---------------- Stage 2: unified scan (short chains per-thread, long chains per-wave) ----------------
__global__ __launch_bounds__(384) void ssm2d_scan(
    const float* __restrict__ dbc, const float* __restrict__ xws,
    const float* __restrict__ bcws, const float* __restrict__ dtwT,
    const float* __restrict__ dtb, const float* __restrict__ Aws,
    const float* __restrict__ Dv, float* __restrict__ out)
{
    const int t = threadIdx.x;
    if (blockIdx.x < SHORT_BLOCKS) {
        const int lp = t / DIN;
        const int d = t - lp * DIN;
        const int p = blockIdx.x * 4 + lp;
        const int q = p & (HW - 1);
        const int r = q >> 7;
        const int c = q & (WW - 1);
        int m = __builtin_ctz(r + 1);
        int mc = __builtin_ctz(c + 1);
        if (mc < m) m = mc;
        if (m >= 5) return;                  // long chains -> tail blocks

        const float* rowd = dbc + (size_t)p * 40;
        float wk[8];
        #pragma unroll
        for (int k = 0; k < 8; ++k) wk[k] = dtwT[k * DIN + d];
        float tb = dtb[d];

        float4 k0 = *reinterpret_cast<const float4*>(rowd);
        float4 k1 = *reinterpret_cast<const float4*>(rowd + 4);
        float tt = tb;
        tt = fmaf(k0.x, wk[0], tt); tt = fmaf(k0.y, wk[1], tt);
        tt = fmaf(k0.z, wk[2], tt); tt = fmaf(k0.w, wk[3], tt);
        tt = fmaf(k1.x, wk[4], tt); tt = fmaf(k1.y, wk[5], tt);
        tt = fmaf(k1.z, wk[6], tt); tt = fmaf(k1.w, wk[7], tt);
        float delta0 = softplus_f(tt);
        float x0 = xws[(size_t)blockIdx.x * 384 + t];
        float y = x0 * fmaf(delta0, bcws[p], Dv[d]);

        if (m >= 1) {
            int L = 1 << m;
            float An[16], acc16[16];
            #pragma unroll
            for (int n = 0; n < 16; ++n) { An[n] = Aws[n * DIN + d]; acc16[n] = 0.f; }
            float S = delta0;
            int pj = p;
            for (int j = 1; j < L; ++j) {
                pj -= DIAG;
                const float* rj = dbc + (size_t)pj * 40;
                float4 j0 = *reinterpret_cast<const float4*>(rj);
                float4 j1 = *reinterpret_cast<const float4*>(rj + 4);
                float t2 = tb;
                t2 = fmaf(j0.x, wk[0], t2); t2 = fmaf(j0.y, wk[1], t2);
                t2 = fmaf(j0.z, wk[2], t2); t2 = fmaf(j0.w, wk[3], t2);
                t2 = fmaf(j1.x, wk[4], t2); t2 = fmaf(j1.y, wk[5], t2);
                t2 = fmaf(j1.z, wk[6], t2); t2 = fmaf(j1.w, wk[7], t2);
                float dj = softplus_f(t2);
                float xj = xws[(size_t)pj * DIN + d];
                float cj = dj * xj;
                float4 B0 = *reinterpret_cast<const float4*>(rj + 8);
                float4 B1 = *reinterpret_cast<const float4*>(rj + 12);
                float4 B2 = *reinterpret_cast<const float4*>(rj + 16);
                float4 B3 = *reinterpret_cast<const float4*>(rj + 20);
                float Bv[16] = {B0.x,B0.y,B0.z,B0.w, B1.x,B1.y,B1.z,B1.w,
                                B2.x,B2.y,B2.z,B2.w, B3.x,B3.y,B3.z,B3.w};
                #pragma unroll
                for (int n = 0; n < 16; ++n)
                    acc16[n] = fmaf(__expf(An[n] * S) * Bv[n], cj, acc16[n]);
                S += dj;
            }
            float4 C0 = *reinterpret_cast<const float4*>(rowd + 24);
            float4 C1 = *reinterpret_cast<const float4*>(rowd + 28);
            float4 C2 = *reinterpret_cast<const float4*>(rowd + 32);
            float4 C3 = *reinterpret_cast<const float4*>(rowd + 36);
            float ys = 0.f;
            ys = fmaf(acc16[0],C0.x,ys); ys = fmaf(acc16[1],C0.y,ys);
            ys = fmaf(acc16[2],C0.z,ys); ys = fmaf(acc16[3],C0.w,ys);
            ys = fmaf(acc16[4],C1.x,ys); ys = fmaf(acc16[5],C1.y,ys);
            ys = fmaf(acc16[6],C1.z,ys); ys = fmaf(acc16[7],C1.w,ys);
            ys = fmaf(acc16[8],C2.x,ys); ys = fmaf(acc16[9],C2.y,ys);
            ys = fmaf(acc16[10],C2.z,ys); ys = fmaf(acc16[11],C2.w,ys);
            ys = fmaf(acc16[12],C3.x,ys); ys = fmaf(acc16[13],C3.y,ys);
            ys = fmaf(acc16[14],C3.z,ys); ys = fmaf(acc16[15],C3.w,ys);
            y += ys;
        }
        out[(size_t)blockIdx.x * 384 + t] = y;
    } else {
        // ---- long chains: one wave per (pixel, d), lane-parallel over j ----
        const int wv = t >> 6;
        const int lane = t & 63;
        int waveid = (blockIdx.x - SHORT_BLOCKS) * 6 + wv;   // 0..3071
        int pix = waveid / DIN;          // 0..31
        int d = waveid - pix * DIN;
        int batch = pix >> 4;
        int sel = pix & 15;
        int r = ((sel >> 2) + 1) * 32 - 1;   // 31,63,95,127
        int c = ((sel & 3) + 1) * 32 - 1;
        int p = batch * HW + r * WW + c;
        int m = __builtin_ctz(r + 1);
        int mc = __builtin_ctz(c + 1);
        if (mc < m) m = mc;
        int L = 1 << m;                      // 32, 64, or 128

        float wk[8];
        #pragma unroll
        for (int k = 0; k < 8; ++k) wk[k] = dtwT[k * DIN + d];   // wave-uniform d
        float tb = dtb[d];
        float An[16];
        #pragma unroll
        for (int n = 0; n < 16; ++n) An[n] = Aws[n * DIN + d];

        float acc16[16];
        #pragma unroll
        for (int n = 0; n < 16; ++n) acc16[n] = 0.0f;
        float Scarry = 0.0f;
        float x0 = 0.0f;

        for (int jb = 0; jb < L; jb += 64) {
            int j = jb + lane;
            bool act = (j < L);
            int jc = act ? j : 0;
            int pj = p - DIAG * jc;
            const float* rj = dbc + (size_t)pj * 40;
            float4 j0 = *reinterpret_cast<const float4*>(rj);
            float4 j1 = *reinterpret_cast<const float4*>(rj + 4);
            float tt = tb;
            tt = fmaf(j0.x, wk[0], tt); tt = fmaf(j0.y, wk[1], tt);
            tt = fmaf(j0.z, wk[2], tt); tt = fmaf(j0.w, wk[3], tt);
            tt = fmaf(j1.x, wk[4], tt); tt = fmaf(j1.y, wk[5], tt);
            tt = fmaf(j1.z, wk[6], tt); tt = fmaf(j1.w, wk[7], tt);
            float dj = softplus_f(tt);
            float xj = xws[(size_t)pj * DIN + d];
            if (!act) { dj = 0.0f; xj = 0.0f; }
            float cj = dj * xj;
            if (jb == 0) x0 = __shfl(xj, 0);

            float incl = dj;
            #pragma unroll
            for (int off = 1; off < 64; off <<= 1) {
                float v = __shfl_up(incl, off);
                if (lane >= off) incl += v;
            }
            float S = Scarry + incl - dj;

            float4 B0 = *reinterpret_cast<const float4*>(rj + 8);
            float4 B1 = *reinterpret_cast<const float4*>(rj + 12);
            float4 B2 = *reinterpret_cast<const float4*>(rj + 16);
            float4 B3 = *reinterpret_cast<const float4*>(rj + 20);
            float Bv[16] = {B0.x,B0.y,B0.z,B0.w, B1.x,B1.y,B1.z,B1.w,
                            B2.x,B2.y,B2.z,B2.w, B3.x,B3.y,B3.z,B3.w};
            #pragma unroll
            for (int n = 0; n < 16; ++n)
                acc16[n] = fmaf(__expf(An[n] * S) * Bv[n], cj, acc16[n]);

            Scarry += __shfl(incl, 63);
        }

        #pragma unroll
        for (int off = 32; off >= 1; off >>= 1) {
            #pragma unroll
            for (int n = 0; n < 16; ++n) acc16[n] += __shfl_xor(acc16[n], off);
        }

        if (lane == 0) {
            const float* rowd = dbc + (size_t)p * 40;
            float4 C0 = *reinterpret_cast<const float4*>(rowd + 24);
            float4 C1 = *reinterpret_cast<const float4*>(rowd + 28);
            float4 C2 = *reinterpret_cast<const float4*>(rowd + 32);
            float4 C3 = *reinterpret_cast<const float4*>(rowd + 36);
            float y = 0.0f;
            y = fmaf(acc16[0],C0.x,y); y = fmaf(acc16[1],C0.y,y);
            y = fmaf(acc16[2],C0.z,y); y = fmaf(acc16[3],C0.w,y);
            y = fmaf(acc16[4],C1.x,y); y = fmaf(acc16[5],C1.y,y);
            y = fmaf(acc16[6],C1.z,y); y = fmaf(acc16[7],C1.w,y);
            y = fmaf(acc16[8],C2.x,y); y = fmaf(acc16[9],C2.y,y);
            y = fmaf(acc16[10],C2.z,y); y = fmaf(acc16[11],C2.w,y);
            y = fmaf(acc16[12],C3.x,y); y = fmaf(acc16[13],C3.y,y);
            y = fmaf(acc16[14],C3.z,y); y = fmaf(acc16[15],C3.w,y);
            y = fmaf(Dv[d], x0, y);
            out[(size_t)p * DIN + d] = y;
        }
    }
}

extern "C" void kernel_launch(void* const* d_in, const int* in_sizes, int n_in,
                              void* d_out, int out_size, void* d_ws, size_t ws_size,
                              hipStream_t stream) {
    const float* x    = (const float*)d_in[0];
    const float* W1   = (const float*)d_in[1];
    const float* b1   = (const float*)d_in[2];
    const float* dtw  = (const float*)d_in[3];
    const float* dtb  = (const float*)d_in[4];
    const float* alog = (const float*)d_in[5];
    const float* Dv   = (const float*)d_in[6];
    float* out = (float*)d_out;

    char* ws = (char*)d_ws;
    float* dbc  = (float*)(ws);                  // NPIX*40*4 = 5,242,880 B
    float* xws  = (float*)(ws + 5242880);        // NPIX*96*4 = 12,582,912 B
    float* bcws = (float*)(ws + 17825792);       // NPIX*4    =   131,072 B
    float* dtwT = (float*)(ws + 17956864);       // 768*4
    float* Aws  = (float*)(ws + 17959936);       // 1536*4

    hipLaunchKernelGGL(ssm2d_dbc, dim3(NPIX / 64), dim3(256), 0, stream,
                       x, W1, b1, dtw, alog, dbc, xws, bcws, dtwT, Aws);
    hipLaunchKernelGGL(ssm2d_scan, dim3(SHORT_BLOCKS + LONG_BLOCKS), dim3(384), 0, stream,
                       dbc, xws, bcws, dtwT, dtb, Aws, Dv, out);
}

// Round 5
// 51.162 us; speedup vs baseline: 1.8709x; 1.2058x over previous
//
#include <hip/hip_runtime.h>
#include <cstdint>

#define CIN 96
#define DIN 96
#define DTR 8
#define DST 16
#define HH 128
#define WW 128
#define HW (HH*WW)
#define NPIX (2*HW)       // B=2
#define DIAG (WW+1)       // diagonal step back = 129
#define SHORT_BLOCKS 2048 // 8192 odd-odd pixels / 4 per block
#define LONG_BLOCKS 512   // 32 px * 96 d = 3072 waves / 6 per block

__device__ __forceinline__ float softplus_f(float t) {
    return (t > 20.0f) ? t : __logf(1.0f + __expf(t));
}

// ---------------- Stage 1: dBC matvec + delta + base output + tables ----------------
// 512 blocks x 256 threads; block = 64 pixels. Wave w computes outputs [10w,10w+10).
__global__ __launch_bounds__(256) void ssm2d_dbc(
    const float* __restrict__ x,
    const float* __restrict__ W1, const float* __restrict__ b1,
    const float* __restrict__ dtw, const float* __restrict__ dtb,
    const float* __restrict__ alog, const float* __restrict__ Dv,
    float* __restrict__ bc, float* __restrict__ xws,
    float* __restrict__ deltag, float* __restrict__ Aws,
    float* __restrict__ out)
{
    __shared__ float sX[CIN][65];     // x tile, padded
    __shared__ float sOut[64][41];    // 40 matvec outputs per pixel, padded
    __shared__ float sBC[64];         // dot(B,C) per pixel

    const int t = threadIdx.x;
    const int p0 = blockIdx.x * 64;
    const int bb = p0 >> 14;
    const int q0 = p0 & (HW - 1);
    const float* xb = x + (size_t)bb * CIN * HW + q0;

    // load x tile (96 ch x 64 px) as float4
    #pragma unroll
    for (int it = 0; it < 6; ++it) {
        int i = it * 256 + t;               // < 1536
        int ch = i >> 4;
        int p4 = (i & 15) << 2;
        float4 v = *reinterpret_cast<const float4*>(xb + (size_t)ch * HW + p4);
        sX[ch][p4 + 0] = v.x; sX[ch][p4 + 1] = v.y;
        sX[ch][p4 + 2] = v.z; sX[ch][p4 + 3] = v.w;
    }
    if (blockIdx.x == 0) {   // one-time transposed A table: Aws[n][d] = -exp(A_log[d][n])
        for (int i = t; i < DIN * DST; i += 256) {
            int d = i >> 4, n = i & 15;
            Aws[n * DIN + d] = -__expf(alog[i]);
        }
    }
    __syncthreads();

    const int lane = t & 63;
    const int w = __builtin_amdgcn_readfirstlane(t >> 6);   // 0..3
    const int og = w * 10;

    float acc[10];
    #pragma unroll
    for (int o = 0; o < 10; ++o) acc[o] = b1[og + o];
    #pragma unroll 16
    for (int ch = 0; ch < CIN; ++ch) {
        float xv = sX[ch][lane];
        #pragma unroll
        for (int o = 0; o < 10; ++o)
            acc[o] = fmaf(xv, W1[(og + o) * CIN + ch], acc[o]);
    }
    #pragma unroll
    for (int o = 0; o < 10; ++o) sOut[lane][og + o] = acc[o];
    __syncthreads();

    if (t < 64) {
        float s = 0.f;
        #pragma unroll
        for (int n = 0; n < DST; ++n) s += sOut[t][8 + n] * sOut[t][24 + n];
        sBC[t] = s;
    }
    __syncthreads();

    // delta = softplus(dtw @ k + dtb); base out = x*(delta*BC + D); both coalesced
    #pragma unroll
    for (int it = 0; it < 24; ++it) {
        int i = it * 256 + t;               // < 6144
        int px = i / 96;
        int d = i - px * 96;
        float tt = dtb[d];
        float4 wA = *reinterpret_cast<const float4*>(dtw + d * DTR);
        float4 wB = *reinterpret_cast<const float4*>(dtw + d * DTR + 4);
        tt = fmaf(sOut[px][0], wA.x, tt); tt = fmaf(sOut[px][1], wA.y, tt);
        tt = fmaf(sOut[px][2], wA.z, tt); tt = fmaf(sOut[px][3], wA.w, tt);
        tt = fmaf(sOut[px][4], wB.x, tt); tt = fmaf(sOut[px][5], wB.y, tt);
        tt = fmaf(sOut[px][6], wB.z, tt); tt = fmaf(sOut[px][7], wB.w, tt);
        float delta = softplus_f(tt);
        deltag[(size_t)p0 * 96 + i] = delta;
        float xv = sX[d][px];
        out[(size_t)p0 * 96 + i] = xv * fmaf(delta, sBC[px], Dv[d]);
    }

    // [B|C] writeout: 64 px x 32 floats, coalesced float4
    #pragma unroll
    for (int it = 0; it < 2; ++it) {
        int i = it * 256 + t;               // < 512
        int px = i >> 3;
        int o4 = (i & 7) << 2;
        float4 v = make_float4(sOut[px][8 + o4], sOut[px][9 + o4],
                               sOut[px][10 + o4], sOut[px][11 + o4]);
        *reinterpret_cast<float4*>(bc + (size_t)(p0 + px) * 32 + o4) = v;
    }
    // xws writeout (pixel-major transpose of x), coalesced float4
    #pragma unroll
    for (int it = 0; it < 6; ++it) {
        int i = it * 256 + t;               // < 1536
        int px = i / 24;
        int c4 = (i - px * 24) << 2;
        float4 v = make_float4(sX[c4][px], sX[c4 + 1][px],
                               sX[c4 + 2][px], sX[c4 + 3][px]);
        *reinterpret_cast<float4*>(xws + (size_t)(p0 + px) * DIN + c4) = v;
    }
}

// ---------------- Stage 2: chain contributions only (m >= 1 pixels) ----------------
__global__ __launch_bounds__(384) void ssm2d_scan(
    const float* __restrict__ bc, const float* __restrict__ xws,
    const float* __restrict__ deltag, const float* __restrict__ Aws,
    float* __restrict__ out)
{
    const int t = threadIdx.x;
    if (blockIdx.x < SHORT_BLOCKS) {
        // ---- short chains: thread per (pixel, d), pixels are odd-row & odd-col ----
        const int lp = t / DIN;
        const int d = t - lp * DIN;
        const int pix = blockIdx.x * 4 + lp;       // 0..8191
        const int b = pix >> 12;
        const int rem = pix & 4095;
        const int r = ((rem >> 6) << 1) + 1;
        const int c = ((rem & 63) << 1) + 1;
        const int p = b * HW + r * WW + c;
        int m = __builtin_ctz(r + 1);
        int mc = __builtin_ctz(c + 1);
        if (mc < m) m = mc;
        if (m >= 5) return;                        // 32 px handled by long path
        const int L = 1 << m;                      // 2..16

        float An[16];
        #pragma unroll
        for (int n = 0; n < 16; ++n) An[n] = Aws[n * DIN + d];
        float acc16[16];
        #pragma unroll
        for (int n = 0; n < 16; ++n) acc16[n] = 0.f;

        float S = deltag[(size_t)p * 96 + d];
        int pj = p;
        for (int j = 1; j < L; ++j) {
            pj -= DIAG;
            float dj = deltag[(size_t)pj * 96 + d];
            float xj = xws[(size_t)pj * 96 + d];
            float cj = dj * xj;
            const float* rb = bc + (size_t)pj * 32;
            float4 B0 = *reinterpret_cast<const float4*>(rb);
            float4 B1 = *reinterpret_cast<const float4*>(rb + 4);
            float4 B2 = *reinterpret_cast<const float4*>(rb + 8);
            float4 B3 = *reinterpret_cast<const float4*>(rb + 12);
            float Bv[16] = {B0.x,B0.y,B0.z,B0.w, B1.x,B1.y,B1.z,B1.w,
                            B2.x,B2.y,B2.z,B2.w, B3.x,B3.y,B3.z,B3.w};
            #pragma unroll
            for (int n = 0; n < 16; ++n)
                acc16[n] = fmaf(__expf(An[n] * S) * Bv[n], cj, acc16[n]);
            S += dj;
        }
        const float* rc = bc + (size_t)p * 32 + 16;
        float4 C0 = *reinterpret_cast<const float4*>(rc);
        float4 C1 = *reinterpret_cast<const float4*>(rc + 4);
        float4 C2 = *reinterpret_cast<const float4*>(rc + 8);
        float4 C3 = *reinterpret_cast<const float4*>(rc + 12);
        float ys = 0.f;
        ys = fmaf(acc16[0],C0.x,ys); ys = fmaf(acc16[1],C0.y,ys);
        ys = fmaf(acc16[2],C0.z,ys); ys = fmaf(acc16[3],C0.w,ys);
        ys = fmaf(acc16[4],C1.x,ys); ys = fmaf(acc16[5],C1.y,ys);
        ys = fmaf(acc16[6],C1.z,ys); ys = fmaf(acc16[7],C1.w,ys);
        ys = fmaf(acc16[8],C2.x,ys); ys = fmaf(acc16[9],C2.y,ys);
        ys = fmaf(acc16[10],C2.z,ys); ys = fmaf(acc16[11],C2.w,ys);
        ys = fmaf(acc16[12],C3.x,ys); ys = fmaf(acc16[13],C3.y,ys);
        ys = fmaf(acc16[14],C3.z,ys); ys = fmaf(acc16[15],C3.w,ys);
        out[(size_t)p * 96 + d] += ys;
    } else {
        // ---- long chains (m >= 5): one wave per (pixel, d), lane-parallel over j ----
        const int wv = t >> 6;
        const int lane = t & 63;
        int waveid = (blockIdx.x - SHORT_BLOCKS) * 6 + wv;   // 0..3071
        int pix = waveid / DIN;          // 0..31
        int d = waveid - pix * DIN;
        int batch = pix >> 4;
        int sel = pix & 15;
        int r = ((sel >> 2) + 1) * 32 - 1;   // 31,63,95,127
        int c = ((sel & 3) + 1) * 32 - 1;
        int p = batch * HW + r * WW + c;
        int m = __builtin_ctz(r + 1);
        int mc = __builtin_ctz(c + 1);
        if (mc < m) m = mc;
        int L = 1 << m;                      // 32, 64, or 128

        float An[16];
        #pragma unroll
        for (int n = 0; n < 16; ++n) An[n] = Aws[n * DIN + d];

        float acc16[16];
        #pragma unroll
        for (int n = 0; n < 16; ++n) acc16[n] = 0.0f;
        float Scarry = 0.0f;

        for (int jb = 0; jb < L; jb += 64) {
            int j = jb + lane;
            bool act = (j < L);
            int jc = act ? j : 0;
            int pj = p - DIAG * jc;
            float dj = deltag[(size_t)pj * 96 + d];
            float xj = xws[(size_t)pj * 96 + d];
            if (!act) dj = 0.0f;
            float cj = (j >= 1 && act) ? dj * xj : 0.0f;   // j=0 term already in out

            float incl = dj;
            #pragma unroll
            for (int off = 1; off < 64; off <<= 1) {
                float v = __shfl_up(incl, off);
                if (lane >= off) incl += v;
            }
            float S = Scarry + incl - dj;

            const float* rb = bc + (size_t)pj * 32;
            float4 B0 = *reinterpret_cast<const float4*>(rb);
            float4 B1 = *reinterpret_cast<const float4*>(rb + 4);
            float4 B2 = *reinterpret_cast<const float4*>(rb + 8);
            float4 B3 = *reinterpret_cast<const float4*>(rb + 12);
            float Bv[16] = {B0.x,B0.y,B0.z,B0.w, B1.x,B1.y,B1.z,B1.w,
                            B2.x,B2.y,B2.z,B2.w, B3.x,B3.y,B3.z,B3.w};
            #pragma unroll
            for (int n = 0; n < 16; ++n)
                acc16[n] = fmaf(__expf(An[n] * S) * Bv[n], cj, acc16[n]);

            Scarry += __shfl(incl, 63);
        }

        #pragma unroll
        for (int off = 32; off >= 1; off >>= 1) {
            #pragma unroll
            for (int n = 0; n < 16; ++n) acc16[n] += __shfl_xor(acc16[n], off);
        }

        if (lane == 0) {
            const float* rc = bc + (size_t)p * 32 + 16;
            float4 C0 = *reinterpret_cast<const float4*>(rc);
            float4 C1 = *reinterpret_cast<const float4*>(rc + 4);
            float4 C2 = *reinterpret_cast<const float4*>(rc + 8);
            float4 C3 = *reinterpret_cast<const float4*>(rc + 12);
            float y = 0.0f;
            y = fmaf(acc16[0],C0.x,y); y = fmaf(acc16[1],C0.y,y);
            y = fmaf(acc16[2],C0.z,y); y = fmaf(acc16[3],C0.w,y);
            y = fmaf(acc16[4],C1.x,y); y = fmaf(acc16[5],C1.y,y);
            y = fmaf(acc16[6],C1.z,y); y = fmaf(acc16[7],C1.w,y);
            y = fmaf(acc16[8],C2.x,y); y = fmaf(acc16[9],C2.y,y);
            y = fmaf(acc16[10],C2.z,y); y = fmaf(acc16[11],C2.w,y);
            y = fmaf(acc16[12],C3.x,y); y = fmaf(acc16[13],C3.y,y);
            y = fmaf(acc16[14],C3.z,y); y = fmaf(acc16[15],C3.w,y);
            out[(size_t)p * 96 + d] += y;
        }
    }
}

extern "C" void kernel_launch(void* const* d_in, const int* in_sizes, int n_in,
                              void* d_out, int out_size, void* d_ws, size_t ws_size,
                              hipStream_t stream) {
    const float* x    = (const float*)d_in[0];
    const float* W1   = (const float*)d_in[1];
    const float* b1   = (const float*)d_in[2];
    const float* dtw  = (const float*)d_in[3];
    const float* dtb  = (const float*)d_in[4];
    const float* alog = (const float*)d_in[5];
    const float* Dv   = (const float*)d_in[6];
    float* out = (float*)d_out;

    char* ws = (char*)d_ws;
    float* deltag = (float*)(ws);                 // NPIX*96*4 = 12,582,912 B
    float* xws    = (float*)(ws + 12582912);      // NPIX*96*4 = 12,582,912 B
    float* bc     = (float*)(ws + 25165824);      // NPIX*32*4 =  4,194,304 B
    float* Aws    = (float*)(ws + 29360128);      // 1536*4

    hipLaunchKernelGGL(ssm2d_dbc, dim3(NPIX / 64), dim3(256), 0, stream,
                       x, W1, b1, dtw, dtb, alog, Dv,
                       bc, xws, deltag, Aws, out);
    hipLaunchKernelGGL(ssm2d_scan, dim3(SHORT_BLOCKS + LONG_BLOCKS), dim3(384), 0, stream,
                       bc, xws, deltag, Aws, out);
}

// Round 6
// 46.184 us; speedup vs baseline: 2.0726x; 1.1078x over previous
//
#include <hip/hip_runtime.h>
#include <cstdint>

#define CIN 96
#define DIN 96
#define DTR 8
#define DST 16
#define HH 128
#define WW 128
#define HW (HH*WW)
#define NPIX (2*HW)       // B=2
#define DIAG (WW+1)       // diagonal step back = 129
#define SHORT_BLOCKS 2048 // 8192 odd-odd pixels / 4 per block
#define LONG_BLOCKS 512   // 32 px * 96 d = 3072 waves / 6 per block

__device__ __forceinline__ float softplus_f(float t) {
    return (t > 20.0f) ? t : __logf(1.0f + __expf(t));
}

// ---------------- Stage 1: dBC matvec + delta + base output + dc pack ----------------
// 512 blocks x 512 threads; block = 64 pixels. Wave w computes outputs [5w,5w+5).
__global__ __launch_bounds__(512) void ssm2d_dbc(
    const float* __restrict__ x,
    const float* __restrict__ W1, const float* __restrict__ b1,
    const float* __restrict__ dtw, const float* __restrict__ dtb,
    const float* __restrict__ alog, const float* __restrict__ Dv,
    float* __restrict__ bc, float2* __restrict__ dc,
    float* __restrict__ Aws, float* __restrict__ out)
{
    __shared__ float sX[CIN][65];     // x tile, padded
    __shared__ float sOut[64][41];    // 40 matvec outputs per pixel, padded
    __shared__ float sBC[64];         // dot(B,C) per pixel

    const int t = threadIdx.x;
    const int p0 = blockIdx.x * 64;
    const int bb = p0 >> 14;
    const int q0 = p0 & (HW - 1);
    const float* xb = x + (size_t)bb * CIN * HW + q0;

    // load x tile (96 ch x 64 px) as float4: 1536 float4 over 512 threads
    #pragma unroll
    for (int it = 0; it < 3; ++it) {
        int i = it * 512 + t;
        int ch = i >> 4;
        int p4 = (i & 15) << 2;
        float4 v = *reinterpret_cast<const float4*>(xb + (size_t)ch * HW + p4);
        sX[ch][p4 + 0] = v.x; sX[ch][p4 + 1] = v.y;
        sX[ch][p4 + 2] = v.z; sX[ch][p4 + 3] = v.w;
    }
    if (blockIdx.x == 0) {   // one-time transposed A table: Aws[n][d] = -exp(A_log[d][n])
        for (int i = t; i < DIN * DST; i += 512) {
            int d = i >> 4, n = i & 15;
            Aws[n * DIN + d] = -__expf(alog[i]);
        }
    }
    __syncthreads();

    const int lane = t & 63;
    const int w = __builtin_amdgcn_readfirstlane(t >> 6);   // 0..7
    const int og = w * 5;

    float a0 = b1[og + 0], a1 = b1[og + 1], a2 = b1[og + 2],
          a3 = b1[og + 3], a4 = b1[og + 4];
    #pragma unroll 16
    for (int ch = 0; ch < CIN; ++ch) {
        float xv = sX[ch][lane];
        a0 = fmaf(xv, W1[(og + 0) * CIN + ch], a0);
        a1 = fmaf(xv, W1[(og + 1) * CIN + ch], a1);
        a2 = fmaf(xv, W1[(og + 2) * CIN + ch], a2);
        a3 = fmaf(xv, W1[(og + 3) * CIN + ch], a3);
        a4 = fmaf(xv, W1[(og + 4) * CIN + ch], a4);
    }
    sOut[lane][og + 0] = a0; sOut[lane][og + 1] = a1; sOut[lane][og + 2] = a2;
    sOut[lane][og + 3] = a3; sOut[lane][og + 4] = a4;
    __syncthreads();

    if (t < 64) {
        float s = 0.f;
        #pragma unroll
        for (int n = 0; n < DST; ++n) s += sOut[t][8 + n] * sOut[t][24 + n];
        sBC[t] = s;
    }
    __syncthreads();

    // delta = softplus(dtw @ k + dtb); base out = x*(delta*BC + D); dc = {delta, delta*x}
    #pragma unroll
    for (int it = 0; it < 12; ++it) {
        int i = it * 512 + t;               // < 6144
        int px = i / 96;
        int d = i - px * 96;
        float tt = dtb[d];
        float4 wA = *reinterpret_cast<const float4*>(dtw + d * DTR);
        float4 wB = *reinterpret_cast<const float4*>(dtw + d * DTR + 4);
        tt = fmaf(sOut[px][0], wA.x, tt); tt = fmaf(sOut[px][1], wA.y, tt);
        tt = fmaf(sOut[px][2], wA.z, tt); tt = fmaf(sOut[px][3], wA.w, tt);
        tt = fmaf(sOut[px][4], wB.x, tt); tt = fmaf(sOut[px][5], wB.y, tt);
        tt = fmaf(sOut[px][6], wB.z, tt); tt = fmaf(sOut[px][7], wB.w, tt);
        float delta = softplus_f(tt);
        float xv = sX[d][px];
        out[(size_t)p0 * 96 + i] = xv * fmaf(delta, sBC[px], Dv[d]);
        dc[(size_t)p0 * 96 + i] = make_float2(delta, delta * xv);
    }

    // [B|C] writeout: 64 px x 32 floats = 512 float4-groups
    {
        int px = t >> 3;
        int o4 = (t & 7) << 2;
        float4 v = make_float4(sOut[px][8 + o4], sOut[px][9 + o4],
                               sOut[px][10 + o4], sOut[px][11 + o4]);
        *reinterpret_cast<float4*>(bc + (size_t)(p0 + px) * 32 + o4) = v;
    }
}

// ---------------- Stage 2: chain contributions only (m >= 1 pixels) ----------------
__global__ __launch_bounds__(384) void ssm2d_scan(
    const float* __restrict__ bc, const float2* __restrict__ dc,
    const float* __restrict__ Aws, float* __restrict__ out)
{
    const int t = threadIdx.x;
    if (blockIdx.x < SHORT_BLOCKS) {
        // ---- short chains: thread per (pixel, d), pixels are odd-row & odd-col ----
        const int lp = t / DIN;
        const int d = t - lp * DIN;
        const int pix = blockIdx.x * 4 + lp;       // 0..8191
        const int b = pix >> 12;
        const int rem = pix & 4095;
        const int r = ((rem >> 6) << 1) + 1;
        const int c = ((rem & 63) << 1) + 1;
        const int p = b * HW + r * WW + c;
        int m = __builtin_ctz(r + 1);
        int mc = __builtin_ctz(c + 1);
        if (mc < m) m = mc;
        if (m >= 5) return;                        // handled by long path
        const int L = 1 << m;                      // 2..16

        float An[16];
        #pragma unroll
        for (int n = 0; n < 16; ++n) An[n] = Aws[n * DIN + d];
        float acc16[16];
        #pragma unroll
        for (int n = 0; n < 16; ++n) acc16[n] = 0.f;

        float S = dc[(size_t)p * 96 + d].x;
        int pj = p;
        for (int j = 1; j < L; ++j) {
            pj -= DIAG;
            float2 v = dc[(size_t)pj * 96 + d];
            float cj = v.y;
            const float* rb = bc + (size_t)pj * 32;
            float4 B0 = *reinterpret_cast<const float4*>(rb);
            float4 B1 = *reinterpret_cast<const float4*>(rb + 4);
            float4 B2 = *reinterpret_cast<const float4*>(rb + 8);
            float4 B3 = *reinterpret_cast<const float4*>(rb + 12);
            float Bv[16] = {B0.x,B0.y,B0.z,B0.w, B1.x,B1.y,B1.z,B1.w,
                            B2.x,B2.y,B2.z,B2.w, B3.x,B3.y,B3.z,B3.w};
            #pragma unroll
            for (int n = 0; n < 16; ++n)
                acc16[n] = fmaf(__expf(An[n] * S) * Bv[n], cj, acc16[n]);
            S += v.x;
        }
        const float* rc = bc + (size_t)p * 32 + 16;
        float4 C0 = *reinterpret_cast<const float4*>(rc);
        float4 C1 = *reinterpret_cast<const float4*>(rc + 4);
        float4 C2 = *reinterpret_cast<const float4*>(rc + 8);
        float4 C3 = *reinterpret_cast<const float4*>(rc + 12);
        float ys = 0.f;
        ys = fmaf(acc16[0],C0.x,ys); ys = fmaf(acc16[1],C0.y,ys);
        ys = fmaf(acc16[2],C0.z,ys); ys = fmaf(acc16[3],C0.w,ys);
        ys = fmaf(acc16[4],C1.x,ys); ys = fmaf(acc16[5],C1.y,ys);
        ys = fmaf(acc16[6],C1.z,ys); ys = fmaf(acc16[7],C1.w,ys);
        ys = fmaf(acc16[8],C2.x,ys); ys = fmaf(acc16[9],C2.y,ys);
        ys = fmaf(acc16[10],C2.z,ys); ys = fmaf(acc16[11],C2.w,ys);
        ys = fmaf(acc16[12],C3.x,ys); ys = fmaf(acc16[13],C3.y,ys);
        ys = fmaf(acc16[14],C3.z,ys); ys = fmaf(acc16[15],C3.w,ys);
        out[(size_t)p * 96 + d] += ys;
    } else {
        // ---- long chains (m >= 5): one wave per (pixel, d), lane-parallel over j ----
        const int wv = t >> 6;
        const int lane = t & 63;
        int waveid = (blockIdx.x - SHORT_BLOCKS) * 6 + wv;   // 0..3071
        int pix = waveid / DIN;          // 0..31
        int d = waveid - pix * DIN;
        int batch = pix >> 4;
        int sel = pix & 15;
        int r = ((sel >> 2) + 1) * 32 - 1;   // 31,63,95,127
        int c = ((sel & 3) + 1) * 32 - 1;
        int p = batch * HW + r * WW + c;
        int m = __builtin_ctz(r + 1);
        int mc = __builtin_ctz(c + 1);
        if (mc < m) m = mc;
        int L = 1 << m;                      // 32, 64, or 128

        float An[16];
        #pragma unroll
        for (int n = 0; n < 16; ++n) An[n] = Aws[n * DIN + d];

        float acc16[16];
        #pragma unroll
        for (int n = 0; n < 16; ++n) acc16[n] = 0.0f;
        float Scarry = 0.0f;

        for (int jb = 0; jb < L; jb += 64) {
            int j = jb + lane;
            bool act = (j < L);
            int jc = act ? j : 0;
            int pj = p - DIAG * jc;
            float2 v = dc[(size_t)pj * 96 + d];
            float dj = act ? v.x : 0.0f;
            float cj = (j >= 1 && act) ? v.y : 0.0f;   // j=0 term already in out

            float incl = dj;
            #pragma unroll
            for (int off = 1; off < 64; off <<= 1) {
                float u = __shfl_up(incl, off);
                if (lane >= off) incl += u;
            }
            float S = Scarry + incl - dj;

            const float* rb = bc + (size_t)pj * 32;
            float4 B0 = *reinterpret_cast<const float4*>(rb);
            float4 B1 = *reinterpret_cast<const float4*>(rb + 4);
            float4 B2 = *reinterpret_cast<const float4*>(rb + 8);
            float4 B3 = *reinterpret_cast<const float4*>(rb + 12);
            float Bv[16] = {B0.x,B0.y,B0.z,B0.w, B1.x,B1.y,B1.z,B1.w,
                            B2.x,B2.y,B2.z,B2.w, B3.x,B3.y,B3.z,B3.w};
            #pragma unroll
            for (int n = 0; n < 16; ++n)
                acc16[n] = fmaf(__expf(An[n] * S) * Bv[n], cj, acc16[n]);

            Scarry += __shfl(incl, 63);
        }

        #pragma unroll
        for (int off = 32; off >= 1; off >>= 1) {
            #pragma unroll
            for (int n = 0; n < 16; ++n) acc16[n] += __shfl_xor(acc16[n], off);
        }

        if (lane == 0) {
            const float* rc = bc + (size_t)p * 32 + 16;
            float4 C0 = *reinterpret_cast<const float4*>(rc);
            float4 C1 = *reinterpret_cast<const float4*>(rc + 4);
            float4 C2 = *reinterpret_cast<const float4*>(rc + 8);
            float4 C3 = *reinterpret_cast<const float4*>(rc + 12);
            float y = 0.0f;
            y = fmaf(acc16[0],C0.x,y); y = fmaf(acc16[1],C0.y,y);
            y = fmaf(acc16[2],C0.z,y); y = fmaf(acc16[3],C0.w,y);
            y = fmaf(acc16[4],C1.x,y); y = fmaf(acc16[5],C1.y,y);
            y = fmaf(acc16[6],C1.z,y); y = fmaf(acc16[7],C1.w,y);
            y = fmaf(acc16[8],C2.x,y); y = fmaf(acc16[9],C2.y,y);
            y = fmaf(acc16[10],C2.z,y); y = fmaf(acc16[11],C2.w,y);
            y = fmaf(acc16[12],C3.x,y); y = fmaf(acc16[13],C3.y,y);
            y = fmaf(acc16[14],C3.z,y); y = fmaf(acc16[15],C3.w,y);
            out[(size_t)p * 96 + d] += y;
        }
    }
}

extern "C" void kernel_launch(void* const* d_in, const int* in_sizes, int n_in,
                              void* d_out, int out_size, void* d_ws, size_t ws_size,
                              hipStream_t stream) {
    const float* x    = (const float*)d_in[0];
    const float* W1   = (const float*)d_in[1];
    const float* b1   = (const float*)d_in[2];
    const float* dtw  = (const float*)d_in[3];
    const float* dtb  = (const float*)d_in[4];
    const float* alog = (const float*)d_in[5];
    const float* Dv   = (const float*)d_in[6];
    float* out = (float*)d_out;

    char* ws = (char*)d_ws;
    float2* dc  = (float2*)(ws);                 // NPIX*96*8 = 25,165,824 B
    float*  bcb = (float*)(ws + 25165824);       // NPIX*32*4 =  4,194,304 B
    float*  Aws = (float*)(ws + 29360128);       // 1536*4

    hipLaunchKernelGGL(ssm2d_dbc, dim3(NPIX / 64), dim3(512), 0, stream,
                       x, W1, b1, dtw, dtb, alog, Dv,
                       bcb, dc, Aws, out);
    hipLaunchKernelGGL(ssm2d_scan, dim3(SHORT_BLOCKS + LONG_BLOCKS), dim3(384), 0, stream,
                       bcb, dc, Aws, out);
}